// Round 5
// baseline (333.875 us; speedup 1.0000x reference)
//
#include <hip/hip_runtime.h>

// ReactionTerm: y_out[b, inds_1p[r]] += y_in[b, inds_1r[r]] * rates_1st[b, r]
//               y_out[b, inds_2p[r]] += y_in[b, i2r0[r]] * y_in[b, i2r1[r]] * rates_2nd[b, r]
// B=1024, N_SPEC=2048, R1=20000, R2=40000.
//
// R9: R8 lesson — conflicts are conserved under instruction-shuffling; they
// track the count of RANDOM bank accesses. Fix both terms:
// (a) 2 rows per block, all LDS arrays interleaved float2 -> every random
//     gather/scatter/RMW is ONE b64 op serving BOTH rows (per-row random ops
//     ~halve; index-decode VALU shared).
// (b) rank-major CSR layout with ODD padded widths: within equal-count sort
//     buckets, lanes read tl at odd strides -> uniform bank load (no hot
//     bank) in phase B. Raw cnt stored, pad slots never read (no zero-fill).
// LDS 62 KB -> 2 blocks/CU (16 waves, ~50% occ — accepted trade).

#define NSPEC 2048
#define BDIM  1024          // rows
#define R1    20000
#define R2    40000
#define CH    2500          // reactions per chunk
#define NCH1  (R1 / CH)     // 8 first-order chunks
#define NCH2  (R2 / CH)     // 16 second-order chunks
#define NCH   (NCH1 + NCH2) // 24
#define TLSZ  3780          // padded CSR slots bound (<= CH + CH/2 = 3750)

// d_ws layout (bytes):
#define WS_PTRR 0                   // uint[NCH*NSPEC] = 196608 B (beg|cnt<<13|s<<21, by rank)
#define WS_E1P  (NCH * NSPEC * 4)   // uint[R1]   = 80000 B (r | csrpos<<11, original order)
#define WS_CSR2 (WS_E1P + R1 * 4)   // ushort[R2] = 80000 B (csrpos, original order)
// total 356608 B

// ---------------------------------------------------------------------------
// One block per chunk: hist -> count-sort ranks -> rank-major odd-width
// layout scan -> csr-position assignment (coalesced by original index).
// ---------------------------------------------------------------------------
__global__ __launch_bounds__(1024) void k_build(
    const int* __restrict__ inds_1r,
    const int* __restrict__ inds_1p, const int* __restrict__ inds_2p,
    uint* __restrict__ ptrr, uint* __restrict__ e1p, ushort* __restrict__ csr2)
{
    __shared__ uint cnt[NSPEC];    // hist, then fill cursors
    __shared__ uint part[1024];
    __shared__ uint wbeg[NSPEC];   // widths by rank, then begs by rank
    __shared__ uint h2[64];        // count histogram (clamped)
    __shared__ uint off[64];       // descending-order rank cursors

    const int c   = blockIdx.x;
    const int tid = threadIdx.x;

    cnt[tid] = 0u; cnt[tid + 1024] = 0u;
    __syncthreads();

    const bool first = (c < NCH1);
    const int  base  = first ? c * CH : (c - NCH1) * CH;
    const int* __restrict__ prod = first ? (inds_1p + base) : (inds_2p + base);

    for (int i = tid; i < CH; i += 1024)
        atomicAdd(&cnt[prod[i]], 1u);
    __syncthreads();

    const uint v0 = cnt[2 * tid], v1 = cnt[2 * tid + 1];

    // Count-sort: histogram of clamped counts -> descending bucket offsets.
    if (tid < 64) h2[tid] = 0u;
    __syncthreads();
    const uint b0 = min(v0, 63u), b1 = min(v1, 63u);
    atomicAdd(&h2[b0], 1u);
    atomicAdd(&h2[b1], 1u);
    __syncthreads();
    if (tid == 0) {
        uint a = 0;
        for (int v = 63; v >= 0; --v) { off[v] = a; a += h2[v]; }
    }
    __syncthreads();
    const uint r0 = atomicAdd(&off[b0], 1u);   // rank of species 2*tid
    const uint r1 = atomicAdd(&off[b1], 1u);   // rank of species 2*tid+1

    // Rank-major layout: width = cnt, padded to odd (0 stays 0).
    const uint w0 = v0 + (((v0 & 1u) == 0u && v0 != 0u) ? 1u : 0u);
    const uint w1 = v1 + (((v1 & 1u) == 0u && v1 != 0u) ? 1u : 0u);
    wbeg[r0] = w0;
    wbeg[r1] = w1;
    __syncthreads();

    // Exclusive scan of widths over 2048 ranks (2 per thread, Hillis-Steele).
    const uint a0 = wbeg[2 * tid], a1 = wbeg[2 * tid + 1];
    const uint ts = a0 + a1;
    part[tid] = ts;
    __syncthreads();
    for (int o = 1; o < 1024; o <<= 1) {
        uint x = (tid >= o) ? part[tid - o] : 0u;
        __syncthreads();
        part[tid] += x;
        __syncthreads();
    }
    const uint run = part[tid] - ts;
    wbeg[2 * tid]     = run;        // exclusive beg by rank
    wbeg[2 * tid + 1] = run + a0;
    __syncthreads();

    const uint beg0 = wbeg[r0], beg1 = wbeg[r1];
    // pack: beg[12:0] | raw cnt[20:13] | species[31:21]
    ptrr[c * NSPEC + r0] = beg0 | (min(v0, 255u) << 13) | ((uint)(2 * tid) << 21);
    ptrr[c * NSPEC + r1] = beg1 | (min(v1, 255u) << 13) | ((uint)(2 * tid + 1) << 21);
    cnt[2 * tid]     = beg0;        // fill cursors by species
    cnt[2 * tid + 1] = beg1;
    __syncthreads();

    // Assign CSR positions; write by ORIGINAL reaction index (coalesced).
    if (first) {
        for (int i = tid; i < CH; i += 1024) {
            const int s = prod[i];
            const uint pos = atomicAdd(&cnt[s], 1u);
            e1p[c * CH + i] = (uint)inds_1r[base + i] | (pos << 11);
        }
    } else {
        for (int i = tid; i < CH; i += 1024) {
            const int s = prod[i];
            const uint pos = atomicAdd(&cnt[s], 1u);
            csr2[base + i] = (ushort)pos;
        }
    }
}

// ---------------------------------------------------------------------------
// Main: 1 block per 2 rows; LDS interleaved float2 (row0,row1). Phase A:
// uniform term computation, one b64 gather serves both rows, b64 tl scatter.
// Phase B: rank-balanced odd-stride contiguous b64 range sums, b64 accl RMW.
// ---------------------------------------------------------------------------
#define MBLOCK 512
#define SPT    (NSPEC / MBLOCK)   // 4 ranks/species per thread

__global__ __launch_bounds__(MBLOCK, 4) void k_main(
    const float* __restrict__ y_in,
    const float* __restrict__ rates_1st,
    const float* __restrict__ rates_2nd,
    const int*   __restrict__ inds_2r,
    const uint*  __restrict__ ptrr,
    const uint*  __restrict__ e1p,
    const ushort* __restrict__ csr2,
    float*       __restrict__ y_out)
{
    __shared__ float2 ysi[NSPEC];   // 16 KB  {row0, row1}
    __shared__ float2 acci[NSPEC];  // 16 KB
    __shared__ float2 tli[TLSZ];    // 30.2 KB -> 62.2 KB total, 2 blocks/CU

    const int b2  = blockIdx.x * 2;
    const int tid = threadIdx.x;

    // Stage 2 rows interleaved.
    {
        const float4 a = ((const float4*)(y_in + (size_t)b2 * NSPEC))[tid];
        const float4 b = ((const float4*)(y_in + (size_t)(b2 + 1) * NSPEC))[tid];
        ysi[4 * tid + 0] = make_float2(a.x, b.x);
        ysi[4 * tid + 1] = make_float2(a.y, b.y);
        ysi[4 * tid + 2] = make_float2(a.z, b.z);
        ysi[4 * tid + 3] = make_float2(a.w, b.w);
        acci[4 * tid + 0] = make_float2(0.f, 0.f);
        acci[4 * tid + 1] = make_float2(0.f, 0.f);
        acci[4 * tid + 2] = make_float2(0.f, 0.f);
        acci[4 * tid + 3] = make_float2(0.f, 0.f);
    }
    __syncthreads();

    for (int c = 0; c < NCH; ++c) {
        // ---- Phase A: per-reaction terms (both rows) -> tli[csr position] ----
        if (c < NCH1) {
            const uint4*  ev  = (const uint4*) (e1p + c * CH);
            const float4* q0v = (const float4*)(rates_1st + (size_t)b2 * R1 + c * CH);
            const float4* q1v = (const float4*)(rates_1st + (size_t)(b2 + 1) * R1 + c * CH);
            for (int i = tid; i < CH / 4; i += MBLOCK) {   // 625 iters
                const uint4  e  = ev[i];
                const float4 q0 = q0v[i];
                const float4 q1 = q1v[i];
                float2 y;
                y = ysi[e.x & 2047u]; tli[e.x >> 11] = make_float2(y.x * q0.x, y.y * q1.x);
                y = ysi[e.y & 2047u]; tli[e.y >> 11] = make_float2(y.x * q0.y, y.y * q1.y);
                y = ysi[e.z & 2047u]; tli[e.z >> 11] = make_float2(y.x * q0.z, y.y * q1.z);
                y = ysi[e.w & 2047u]; tli[e.w >> 11] = make_float2(y.x * q0.w, y.y * q1.w);
            }
        } else {
            const int c2 = c - NCH1;
            const uint4*   iv  = (const uint4*)  (inds_2r + 2 * (c2 * CH));
            const float4*  q0v = (const float4*) (rates_2nd + (size_t)b2 * R2 + c2 * CH);
            const float4*  q1v = (const float4*) (rates_2nd + (size_t)(b2 + 1) * R2 + c2 * CH);
            const ushort4* pv  = (const ushort4*)(csr2 + c2 * CH);
            for (int i = tid; i < CH / 4; i += MBLOCK) {   // 625 iters, 4 reactions
                const uint4   ia = iv[2 * i];
                const uint4   ib = iv[2 * i + 1];
                const float4  q0 = q0v[i];
                const float4  q1 = q1v[i];
                const ushort4 p  = pv[i];
                float2 ya, yb;
                ya = ysi[ia.x]; yb = ysi[ia.y];
                tli[p.x] = make_float2(ya.x * yb.x * q0.x, ya.y * yb.y * q1.x);
                ya = ysi[ia.z]; yb = ysi[ia.w];
                tli[p.y] = make_float2(ya.x * yb.x * q0.y, ya.y * yb.y * q1.y);
                ya = ysi[ib.x]; yb = ysi[ib.y];
                tli[p.z] = make_float2(ya.x * yb.x * q0.z, ya.y * yb.y * q1.z);
                ya = ysi[ib.z]; yb = ysi[ib.w];
                tli[p.w] = make_float2(ya.x * yb.x * q0.w, ya.y * yb.y * q1.w);
            }
        }
        __syncthreads();

        // ---- Phase B: rank-balanced odd-stride range sums (both rows) ----
        const uint* pr = ptrr + c * NSPEC;
        #pragma unroll
        for (int k = 0; k < SPT; ++k) {
            const uint v = pr[k * MBLOCK + tid];   // coalesced b32
            uint       j = v & 0x1FFFu;
            uint       n = (v >> 13) & 0xFFu;
            const uint s = v >> 21;
            float a0 = 0.f, a1 = 0.f;
            for (; n > 0; --n, ++j) {
                const float2 t = tli[j];
                a0 += t.x; a1 += t.y;
            }
            const float2 cu = acci[s];             // exclusive owner this chunk
            acci[s] = make_float2(cu.x + a0, cu.y + a1);
        }
        __syncthreads();   // before next chunk overwrites tli
    }

    // Coalesced writeback, both rows.
    float* o0 = y_out + (size_t)b2 * NSPEC;
    float* o1 = o0 + NSPEC;
    #pragma unroll
    for (int k = 0; k < SPT; ++k) {
        const int s = k * MBLOCK + tid;
        const float2 v = acci[s];
        o0[s] = v.x;
        o1[s] = v.y;
    }
}

extern "C" void kernel_launch(void* const* d_in, const int* in_sizes, int n_in,
                              void* d_out, int out_size, void* d_ws, size_t ws_size,
                              hipStream_t stream) {
    const float* y_in      = (const float*)d_in[0];
    const float* rates_1st = (const float*)d_in[1];
    const float* rates_2nd = (const float*)d_in[2];
    const int*   inds_1r   = (const int*)d_in[3];
    const int*   inds_1p   = (const int*)d_in[4];
    const int*   inds_2r   = (const int*)d_in[5];
    const int*   inds_2p   = (const int*)d_in[6];
    float*       y_out     = (float*)d_out;

    char* ws = (char*)d_ws;
    uint*   ptrr = (uint*)  (ws + WS_PTRR);
    uint*   e1p  = (uint*)  (ws + WS_E1P);
    ushort* csr2 = (ushort*)(ws + WS_CSR2);

    // Build CSR metadata every call (d_ws is re-poisoned).
    k_build<<<NCH, 1024, 0, stream>>>(inds_1r, inds_1p, inds_2p, ptrr, e1p, csr2);
    k_main<<<BDIM / 2, MBLOCK, 0, stream>>>(y_in, rates_1st, rates_2nd, inds_2r,
                                            ptrr, e1p, csr2, y_out);
}

// Round 6
// 323.490 us; speedup vs baseline: 1.0321x; 1.0321x over previous
//
#include <hip/hip_runtime.h>

// ReactionTerm: y_out[b, inds_1p[r]] += y_in[b, inds_1r[r]] * rates_1st[b, r]
//               y_out[b, inds_2p[r]] += y_in[b, i2r0[r]] * y_in[b, i2r1[r]] * rates_2nd[b, r]
// B=1024, N_SPEC=2048, R1=20000, R2=40000.
//
// R10: R9 post-mortem — per-op economy landed (conflicts 2.21e7->1.45e7,
// VALU shared) but occupancy halved (82->43%) and time was flat: regime is
// time ~ LDS-work / occupancy-efficiency. Fix is geometric: MBLOCK 512->1024
// keeps 2 rows + same 62KB LDS per block, but 2 blocks/CU now = 32 waves =
// 100% occupancy (126976B <= 160KB; 52 VGPR <= 64 so 8 waves/SIMD legal).
// Plus: phase B skips n==0 ranks (count-sort makes the zero bucket
// wave-uniform; ~29% of ranks -> no loop, no acci RMW, no divergence).

#define NSPEC 2048
#define BDIM  1024          // rows
#define R1    20000
#define R2    40000
#define CH    2500          // reactions per chunk
#define NCH1  (R1 / CH)     // 8 first-order chunks
#define NCH2  (R2 / CH)     // 16 second-order chunks
#define NCH   (NCH1 + NCH2) // 24
#define TLSZ  3780          // padded CSR slots bound (<= CH + CH/2 = 3750)

// d_ws layout (bytes):
#define WS_PTRR 0                   // uint[NCH*NSPEC] = 196608 B (beg|cnt<<13|s<<21, by rank)
#define WS_E1P  (NCH * NSPEC * 4)   // uint[R1]   = 80000 B (r | csrpos<<11, original order)
#define WS_CSR2 (WS_E1P + R1 * 4)   // ushort[R2] = 80000 B (csrpos, original order)
// total 356608 B

// ---------------------------------------------------------------------------
// One block per chunk: hist -> count-sort ranks -> rank-major odd-width
// layout scan -> csr-position assignment (coalesced by original index).
// ---------------------------------------------------------------------------
__global__ __launch_bounds__(1024) void k_build(
    const int* __restrict__ inds_1r,
    const int* __restrict__ inds_1p, const int* __restrict__ inds_2p,
    uint* __restrict__ ptrr, uint* __restrict__ e1p, ushort* __restrict__ csr2)
{
    __shared__ uint cnt[NSPEC];    // hist, then fill cursors
    __shared__ uint part[1024];
    __shared__ uint wbeg[NSPEC];   // widths by rank, then begs by rank
    __shared__ uint h2[64];        // count histogram (clamped)
    __shared__ uint off[64];       // descending-order rank cursors

    const int c   = blockIdx.x;
    const int tid = threadIdx.x;

    cnt[tid] = 0u; cnt[tid + 1024] = 0u;
    __syncthreads();

    const bool first = (c < NCH1);
    const int  base  = first ? c * CH : (c - NCH1) * CH;
    const int* __restrict__ prod = first ? (inds_1p + base) : (inds_2p + base);

    for (int i = tid; i < CH; i += 1024)
        atomicAdd(&cnt[prod[i]], 1u);
    __syncthreads();

    const uint v0 = cnt[2 * tid], v1 = cnt[2 * tid + 1];

    // Count-sort: histogram of clamped counts -> descending bucket offsets.
    if (tid < 64) h2[tid] = 0u;
    __syncthreads();
    const uint b0 = min(v0, 63u), b1 = min(v1, 63u);
    atomicAdd(&h2[b0], 1u);
    atomicAdd(&h2[b1], 1u);
    __syncthreads();
    if (tid == 0) {
        uint a = 0;
        for (int v = 63; v >= 0; --v) { off[v] = a; a += h2[v]; }
    }
    __syncthreads();
    const uint r0 = atomicAdd(&off[b0], 1u);   // rank of species 2*tid
    const uint r1 = atomicAdd(&off[b1], 1u);   // rank of species 2*tid+1

    // Rank-major layout: width = cnt, padded to odd (0 stays 0).
    const uint w0 = v0 + (((v0 & 1u) == 0u && v0 != 0u) ? 1u : 0u);
    const uint w1 = v1 + (((v1 & 1u) == 0u && v1 != 0u) ? 1u : 0u);
    wbeg[r0] = w0;
    wbeg[r1] = w1;
    __syncthreads();

    // Exclusive scan of widths over 2048 ranks (2 per thread, Hillis-Steele).
    const uint a0 = wbeg[2 * tid], a1 = wbeg[2 * tid + 1];
    const uint ts = a0 + a1;
    part[tid] = ts;
    __syncthreads();
    for (int o = 1; o < 1024; o <<= 1) {
        uint x = (tid >= o) ? part[tid - o] : 0u;
        __syncthreads();
        part[tid] += x;
        __syncthreads();
    }
    const uint run = part[tid] - ts;
    wbeg[2 * tid]     = run;        // exclusive beg by rank
    wbeg[2 * tid + 1] = run + a0;
    __syncthreads();

    const uint beg0 = wbeg[r0], beg1 = wbeg[r1];
    // pack: beg[12:0] | raw cnt[20:13] | species[31:21]
    ptrr[c * NSPEC + r0] = beg0 | (min(v0, 255u) << 13) | ((uint)(2 * tid) << 21);
    ptrr[c * NSPEC + r1] = beg1 | (min(v1, 255u) << 13) | ((uint)(2 * tid + 1) << 21);
    cnt[2 * tid]     = beg0;        // fill cursors by species
    cnt[2 * tid + 1] = beg1;
    __syncthreads();

    // Assign CSR positions; write by ORIGINAL reaction index (coalesced).
    if (first) {
        for (int i = tid; i < CH; i += 1024) {
            const int s = prod[i];
            const uint pos = atomicAdd(&cnt[s], 1u);
            e1p[c * CH + i] = (uint)inds_1r[base + i] | (pos << 11);
        }
    } else {
        for (int i = tid; i < CH; i += 1024) {
            const int s = prod[i];
            const uint pos = atomicAdd(&cnt[s], 1u);
            csr2[base + i] = (ushort)pos;
        }
    }
}

// ---------------------------------------------------------------------------
// Main: 1 block (1024 thr) per 2 rows; LDS interleaved float2 {row0,row1}.
// Phase A: uniform terms, one b64 gather serves both rows, b64 tl scatter.
// Phase B: rank-balanced odd-stride b64 range sums; n==0 ranks skipped
// (wave-uniform via count-sort); b64 acci RMW once per nonzero species.
// ---------------------------------------------------------------------------
#define MBLOCK 1024
#define SPT    (NSPEC / MBLOCK)   // 2 ranks/species per thread

__global__ __launch_bounds__(MBLOCK, 2) void k_main(
    const float* __restrict__ y_in,
    const float* __restrict__ rates_1st,
    const float* __restrict__ rates_2nd,
    const int*   __restrict__ inds_2r,
    const uint*  __restrict__ ptrr,
    const uint*  __restrict__ e1p,
    const ushort* __restrict__ csr2,
    float*       __restrict__ y_out)
{
    __shared__ float2 ysi[NSPEC];   // 16 KB  {row0, row1}
    __shared__ float2 acci[NSPEC];  // 16 KB
    __shared__ float2 tli[TLSZ];    // 30.2 KB -> 62.2 KB total, 2 blocks/CU = 32 waves

    const int b2  = blockIdx.x * 2;
    const int tid = threadIdx.x;

    // Stage 2 rows interleaved (1024 threads x float2 each).
    {
        const float2 a = ((const float2*)(y_in + (size_t)b2 * NSPEC))[tid];
        const float2 b = ((const float2*)(y_in + (size_t)(b2 + 1) * NSPEC))[tid];
        ysi[2 * tid + 0] = make_float2(a.x, b.x);
        ysi[2 * tid + 1] = make_float2(a.y, b.y);
        acci[2 * tid + 0] = make_float2(0.f, 0.f);
        acci[2 * tid + 1] = make_float2(0.f, 0.f);
    }
    __syncthreads();

    for (int c = 0; c < NCH; ++c) {
        // ---- Phase A: per-reaction terms (both rows) -> tli[csr position] ----
        if (c < NCH1) {
            const uint4*  ev  = (const uint4*) (e1p + c * CH);
            const float4* q0v = (const float4*)(rates_1st + (size_t)b2 * R1 + c * CH);
            const float4* q1v = (const float4*)(rates_1st + (size_t)(b2 + 1) * R1 + c * CH);
            for (int i = tid; i < CH / 4; i += MBLOCK) {   // 625 iters
                const uint4  e  = ev[i];
                const float4 q0 = q0v[i];
                const float4 q1 = q1v[i];
                float2 y;
                y = ysi[e.x & 2047u]; tli[e.x >> 11] = make_float2(y.x * q0.x, y.y * q1.x);
                y = ysi[e.y & 2047u]; tli[e.y >> 11] = make_float2(y.x * q0.y, y.y * q1.y);
                y = ysi[e.z & 2047u]; tli[e.z >> 11] = make_float2(y.x * q0.z, y.y * q1.z);
                y = ysi[e.w & 2047u]; tli[e.w >> 11] = make_float2(y.x * q0.w, y.y * q1.w);
            }
        } else {
            const int c2 = c - NCH1;
            const uint4*   iv  = (const uint4*)  (inds_2r + 2 * (c2 * CH));
            const float4*  q0v = (const float4*) (rates_2nd + (size_t)b2 * R2 + c2 * CH);
            const float4*  q1v = (const float4*) (rates_2nd + (size_t)(b2 + 1) * R2 + c2 * CH);
            const ushort4* pv  = (const ushort4*)(csr2 + c2 * CH);
            for (int i = tid; i < CH / 4; i += MBLOCK) {   // 625 iters, 4 reactions
                const uint4   ia = iv[2 * i];
                const uint4   ib = iv[2 * i + 1];
                const float4  q0 = q0v[i];
                const float4  q1 = q1v[i];
                const ushort4 p  = pv[i];
                float2 ya, yb;
                ya = ysi[ia.x]; yb = ysi[ia.y];
                tli[p.x] = make_float2(ya.x * yb.x * q0.x, ya.y * yb.y * q1.x);
                ya = ysi[ia.z]; yb = ysi[ia.w];
                tli[p.y] = make_float2(ya.x * yb.x * q0.y, ya.y * yb.y * q1.y);
                ya = ysi[ib.x]; yb = ysi[ib.y];
                tli[p.z] = make_float2(ya.x * yb.x * q0.z, ya.y * yb.y * q1.z);
                ya = ysi[ib.z]; yb = ysi[ib.w];
                tli[p.w] = make_float2(ya.x * yb.x * q0.w, ya.y * yb.y * q1.w);
            }
        }
        __syncthreads();

        // ---- Phase B: rank-balanced odd-stride range sums (both rows) ----
        const uint* pr = ptrr + c * NSPEC;
        #pragma unroll
        for (int k = 0; k < SPT; ++k) {
            const uint v = pr[k * MBLOCK + tid];   // coalesced b32
            uint       n = (v >> 13) & 0xFFu;
            if (n) {                               // zero bucket: wave-uniform skip
                uint       j = v & 0x1FFFu;
                const uint s = v >> 21;
                float a0 = 0.f, a1 = 0.f;
                for (; n > 0; --n, ++j) {
                    const float2 t = tli[j];
                    a0 += t.x; a1 += t.y;
                }
                const float2 cu = acci[s];         // exclusive owner this chunk
                acci[s] = make_float2(cu.x + a0, cu.y + a1);
            }
        }
        __syncthreads();   // before next chunk overwrites tli
    }

    // Coalesced writeback, both rows.
    float* o0 = y_out + (size_t)b2 * NSPEC;
    float* o1 = o0 + NSPEC;
    #pragma unroll
    for (int k = 0; k < SPT; ++k) {
        const int s = k * MBLOCK + tid;
        const float2 v = acci[s];
        o0[s] = v.x;
        o1[s] = v.y;
    }
}

extern "C" void kernel_launch(void* const* d_in, const int* in_sizes, int n_in,
                              void* d_out, int out_size, void* d_ws, size_t ws_size,
                              hipStream_t stream) {
    const float* y_in      = (const float*)d_in[0];
    const float* rates_1st = (const float*)d_in[1];
    const float* rates_2nd = (const float*)d_in[2];
    const int*   inds_1r   = (const int*)d_in[3];
    const int*   inds_1p   = (const int*)d_in[4];
    const int*   inds_2r   = (const int*)d_in[5];
    const int*   inds_2p   = (const int*)d_in[6];
    float*       y_out     = (float*)d_out;

    char* ws = (char*)d_ws;
    uint*   ptrr = (uint*)  (ws + WS_PTRR);
    uint*   e1p  = (uint*)  (ws + WS_E1P);
    ushort* csr2 = (ushort*)(ws + WS_CSR2);

    // Build CSR metadata every call (d_ws is re-poisoned).
    k_build<<<NCH, 1024, 0, stream>>>(inds_1r, inds_1p, inds_2p, ptrr, e1p, csr2);
    k_main<<<BDIM / 2, MBLOCK, 0, stream>>>(y_in, rates_1st, rates_2nd, inds_2r,
                                            ptrr, e1p, csr2, y_out);
}